// Round 3
// baseline (227.321 us; speedup 1.0000x reference)
//
#include <hip/hip_runtime.h>
#include <math.h>

#define BB 8
#define NCC 1024
#define NTT 1024
#define HH 128
#define DYY 32
#define NTB 16                   // 512 blocks x 512 threads -> 2 blocks/CU
#define LOG2E 1.44269504088896340736f

// LDS arena: 13808 floats = 55.2 KB (x2 blocks = 110 KB <= 160 KB/CU; round-1
// measurement proved 2 blocks co-reside at 34.8 KB => the "64 KB model" is
// wrong, real budget is 160 KB).
//   HB   [0,2112)      h: 16 x 132 (cross-wave shared -> the ONLY barriers)
//   RED  [2112,2496)   8 waves x 48 sig partials
//   WCH  [2496,6592)   8 waves x 2 bufs x 256: wave-PRIVATE W chunks (phase 1)
//   YCB  [6592,10688)  8 waves x 2 bufs x 256: wave-PRIVATE yc tiles (phase 2)
//   XCB  [10688,13760) 8 waves x 384: wave-private xc rows (phase 2)
//   SIGL [13760,13808)
//   CMB  [0,4224) + SL [4224,4352): epilogue, aliases HB/RED/WCH (all dead;
//        disjoint from YCB/XCB/SIGL so fast-wave deposits can't race slow waves)
#define HB 0
#define RED 2112
#define WCH 2496
#define YCB 6592
#define XCB 10688
#define SIGL 13760
#define SMEM_SZ 13808
#define CMB 0
#define SL 4224
#define HSTRIDE 132              // mult of 4 (aligned b128); p vs p+8 = 2-way = free

// Wave-autonomous design: W cols [16w,16w+16) and yc rows [128w,128w+128) are
// read ONLY by wave w (no cross-wave sharing), so staging is wave-private LDS
// double-buffering with compiler-managed vmcnt/lgkmcnt -- NO __syncthreads in
// either pipeline. Only h (cross-wave) and sigl need barriers: 5 total.
// Phase 2 e-dedup: each thread computes 2 exp per tile, partner pair comes via
// shfl_xor(16) (dg axis). P<=0 => exp(P)<=1: no max subtraction.

#define ACC16(E, PTR)                                                          \
    do {                                                                       \
        const float4* yv_ = (const float4*)(PTR);                              \
        const float4 q0_ = yv_[0], q1_ = yv_[1], q2_ = yv_[2], q3_ = yv_[3];   \
        acc[0] = fmaf(E, q0_.x, acc[0]);                                       \
        acc[1] = fmaf(E, q0_.y, acc[1]);                                       \
        acc[2] = fmaf(E, q0_.z, acc[2]);                                       \
        acc[3] = fmaf(E, q0_.w, acc[3]);                                       \
        acc[4] = fmaf(E, q1_.x, acc[4]);                                       \
        acc[5] = fmaf(E, q1_.y, acc[5]);                                       \
        acc[6] = fmaf(E, q1_.z, acc[6]);                                       \
        acc[7] = fmaf(E, q1_.w, acc[7]);                                       \
        acc[8] = fmaf(E, q2_.x, acc[8]);                                       \
        acc[9] = fmaf(E, q2_.y, acc[9]);                                       \
        acc[10] = fmaf(E, q2_.z, acc[10]);                                     \
        acc[11] = fmaf(E, q2_.w, acc[11]);                                     \
        acc[12] = fmaf(E, q3_.x, acc[12]);                                     \
        acc[13] = fmaf(E, q3_.y, acc[13]);                                     \
        acc[14] = fmaf(E, q3_.z, acc[14]);                                     \
        acc[15] = fmaf(E, q3_.w, acc[15]);                                     \
    } while (0)

__global__ __launch_bounds__(512, 4) void k_fused(const float* __restrict__ xc,
                                                  const float* __restrict__ yc,
                                                  const float* __restrict__ xt,
                                                  const float* __restrict__ W0,
                                                  const float* __restrict__ b0,
                                                  const float* __restrict__ W1,
                                                  const float* __restrict__ b1,
                                                  const float* __restrict__ W2,
                                                  const float* __restrict__ b2,
                                                  const float* __restrict__ W3,
                                                  const float* __restrict__ b3,
                                                  float* __restrict__ out) {
    const int tid = threadIdx.x;
    const int t0 = blockIdx.x * NTB;     // global target base (xt/out flat B*Nt)
    const int b = blockIdx.x >> 6;       // 64 blocks per batch
    const int wv = tid >> 6;             // wave 0..7
    const int lane = tid & 63;

    __shared__ float smem[SMEM_SZ];

    const float4* __restrict__ ycG4 = (const float4*)(yc + (size_t)b * NCC * DYY);
    const float4* __restrict__ xcG4 = (const float4*)(xc + (size_t)b * NCC * 3);

    float* ycw = smem + YCB + wv * 512;  // wave-private: 2 bufs x 256 floats
    float* xcw = smem + XCB + wv * 384;  // wave-private: 128 rows x 3
    const int ybase = wv * 1024;         // f4 index of wave's first yc row

    // ---- phase-2 staging loads issued FIRST: latency hides under phase 1 ----
    float4 ty0 = ycG4[ybase + lane];            // tile 0
    float4 ty1 = ycG4[ybase + 64 + lane];       // tile 1
    float4 tx0, tx1;
    if (lane < 48) {
        tx0 = xcG4[wv * 96 + lane];
        tx1 = xcG4[wv * 96 + 48 + lane];
    }

    // ================= phase 1: MLP =================
    const int jg = tid >> 4;             // 0..31 col-group (4 cols)
    const int p = tid & 15;              // 0..15 point
    const int j0 = jg * 4;
    const int jl4 = (jg & 3) * 4;        // col offset within the wave's W slice
    float* hrow = smem + HB + p * HSTRIDE;

    // ---- L0 (W0 columns as float4, broadcast) ----
    {
        const float* xr = xt + (size_t)(t0 + p) * 3;
        const float x0 = xr[0], x1 = xr[1], x2 = xr[2];
        const float4* W0v = (const float4*)W0;
        const float4 w0a = W0v[jg], w0b = W0v[32 + jg], w0c = W0v[64 + jg];
        const float4 bb0 = ((const float4*)b0)[jg];
        float4 h0;
        h0.x = fmaxf(fmaf(x0, w0a.x, fmaf(x1, w0b.x, fmaf(x2, w0c.x, bb0.x))), 0.f);
        h0.y = fmaxf(fmaf(x0, w0a.y, fmaf(x1, w0b.y, fmaf(x2, w0c.y, bb0.y))), 0.f);
        h0.z = fmaxf(fmaf(x0, w0a.z, fmaf(x1, w0b.z, fmaf(x2, w0c.z, bb0.z))), 0.f);
        h0.w = fmaxf(fmaf(x0, w0a.w, fmaf(x1, w0b.w, fmaf(x2, w0c.w, bb0.w))), 0.f);
        *(float4*)(hrow + j0) = h0;
    }

    // ---- park phase-2 staged data in its (disjoint) LDS while L0 settles ----
    ((float4*)ycw)[lane] = ty0;
    ((float4*)(ycw + 256))[lane] = ty1;
    if (lane < 48) {
        ((float4*)xcw)[lane] = tx0;
        ((float4*)xcw)[lane + 48] = tx1;
    }

    // wave-private W chunk pipeline: chunk = 16 k-rows x 16 cols = 1 f4/lane
    const int gWb = (lane >> 2) * 32 + wv * 4 + (lane & 3);
    float* wwb = smem + WCH + wv * 512;
    const float4* __restrict__ W1v = (const float4*)W1;
    const float4* __restrict__ W2v = (const float4*)W2;

    // L1 prologue loads BEFORE the barrier (independent of LDS)
    float4 wA0 = W1v[gWb], wA1 = W1v[gWb + 512];
    __syncthreads();                     // h(L0) visible to all waves

    auto run_layer = [&](const float4* __restrict__ Wv, const float4 bi,
                         float4 r0, float4 r1) -> float4 {
        float a0 = bi.x, a1 = bi.y, a2 = bi.z, a3 = bi.w;
        ((float4*)wwb)[lane] = r0;       // buf0 = chunk 0 (waits its vmcnt)
        float4 wcur = r1;                // chunk 1 pending in reg
#pragma unroll
        for (int c = 0; c < 8; ++c) {
            float4 wnext;
            if (c < 6) wnext = Wv[gWb + (c + 2) * 512];           // issue early
            if (c < 7) ((float4*)(wwb + ((c + 1) & 1) * 256))[lane] = wcur;
            const float* wbc = wwb + (c & 1) * 256;
#pragma unroll
            for (int q = 0; q < 4; ++q) {
                const float4 ch = *(const float4*)(hrow + c * 16 + q * 4);
                const float4 k0 = *(const float4*)(wbc + (q * 4 + 0) * 16 + jl4);
                const float4 k1 = *(const float4*)(wbc + (q * 4 + 1) * 16 + jl4);
                const float4 k2 = *(const float4*)(wbc + (q * 4 + 2) * 16 + jl4);
                const float4 k3 = *(const float4*)(wbc + (q * 4 + 3) * 16 + jl4);
                a0 = fmaf(ch.x, k0.x, a0);
                a1 = fmaf(ch.x, k0.y, a1);
                a2 = fmaf(ch.x, k0.z, a2);
                a3 = fmaf(ch.x, k0.w, a3);
                a0 = fmaf(ch.y, k1.x, a0);
                a1 = fmaf(ch.y, k1.y, a1);
                a2 = fmaf(ch.y, k1.z, a2);
                a3 = fmaf(ch.y, k1.w, a3);
                a0 = fmaf(ch.z, k2.x, a0);
                a1 = fmaf(ch.z, k2.y, a1);
                a2 = fmaf(ch.z, k2.z, a2);
                a3 = fmaf(ch.z, k2.w, a3);
                a0 = fmaf(ch.w, k3.x, a0);
                a1 = fmaf(ch.w, k3.y, a1);
                a2 = fmaf(ch.w, k3.z, a2);
                a3 = fmaf(ch.w, k3.w, a3);
            }
            wcur = wnext;
        }
        float4 r;
        r.x = fmaxf(a0, 0.f);
        r.y = fmaxf(a1, 0.f);
        r.z = fmaxf(a2, 0.f);
        r.w = fmaxf(a3, 0.f);
        return r;
    };

    float4 oL1 = run_layer(W1v, ((const float4*)b1)[jg], wA0, wA1);
    float4 wB0 = W2v[gWb], wB1 = W2v[gWb + 512];   // L2 prologue before barriers
    __syncthreads();                     // all h(L0) reads done
    *(float4*)(hrow + j0) = oL1;
    __syncthreads();                     // h(L1) visible
    float4 oL2 = run_layer(W2v, ((const float4*)b2)[jg], wB0, wB1);

    // ---- L3 + shfl-reduce over jg + exp -> sig*log2e ----
    {
        const float4* W3v = (const float4*)W3;
        const float4 wr0 = W3v[jg * 3 + 0];
        const float4 wr1 = W3v[jg * 3 + 1];
        const float4 wr2 = W3v[jg * 3 + 2];
        float p0 = oL2.x * wr0.x + oL2.y * wr0.w + oL2.z * wr1.z + oL2.w * wr2.y;
        float p1 = oL2.x * wr0.y + oL2.y * wr1.x + oL2.z * wr1.w + oL2.w * wr2.z;
        float p2 = oL2.x * wr0.z + oL2.y * wr1.y + oL2.z * wr2.x + oL2.w * wr2.w;
        p0 += __shfl_xor(p0, 16, 64);    // lane bits 4,5 = jg&3: reduce 4 jg
        p0 += __shfl_xor(p0, 32, 64);
        p1 += __shfl_xor(p1, 16, 64);
        p1 += __shfl_xor(p1, 32, 64);
        p2 += __shfl_xor(p2, 16, 64);
        p2 += __shfl_xor(p2, 32, 64);
        if (lane < 16) {                 // lane = p here
            smem[RED + wv * 48 + lane * 3 + 0] = p0;
            smem[RED + wv * 48 + lane * 3 + 1] = p1;
            smem[RED + wv * 48 + lane * 3 + 2] = p2;
        }
    }
    __syncthreads();
    if (tid < 48) {
        const int r = tid / 3, cix = tid - r * 3;
        float v = b3[cix];
#pragma unroll
        for (int g = 0; g < 8; ++g) v += smem[RED + g * 48 + r * 3 + cix];
        smem[SIGL + r * 3 + cix] = __expf(v) * LOG2E;
    }
    __syncthreads();                     // sigl ready; phase-1 arenas dead

    // ========== phase 2: attention, wave-autonomous, ZERO barriers ==========
    const int tl = lane & 15;            // target within block
    const int dg = (lane >> 4) & 1;      // d-half
    const int ns = lane >> 5;            // n-half within the wave's 8-row tile
    const int dg16 = dg * 16;
    const int rown = ns * 4 + dg * 2;        // own e rows
    const int rowo = ns * 4 + 2 - dg * 2;    // partner e rows (via shfl)

    const float s0 = smem[SIGL + tl * 3 + 0];
    const float s1 = smem[SIGL + tl * 3 + 1];
    const float s2 = smem[SIGL + tl * 3 + 2];
    const float* ar = xt + (size_t)(t0 + tl) * 3;
    const float a0 = ar[0], a1 = ar[1], a2 = ar[2];

    float acc[16];
#pragma unroll
    for (int i = 0; i < 16; ++i) acc[i] = 0.f;
    float l = 0.f;

#pragma unroll 2
    for (int t = 0; t < 16; ++t) {
        float4 ynext;
        if (t < 14) ynext = ycG4[ybase + (t + 2) * 64 + lane];   // issue early
        const float* yb = ycw + (t & 1) * 256;
        const float* xb = xcw + t * 24;

        float d0 = xb[rown * 3 + 0] - a0;
        float d1 = xb[rown * 3 + 1] - a1;
        float d2 = xb[rown * 3 + 2] - a2;
        float pp = fmaf(s0, d0 * d0, fmaf(s1, d1 * d1, s2 * (d2 * d2)));
        const float eo0 = exp2f(-pp);
        d0 = xb[rown * 3 + 3] - a0;
        d1 = xb[rown * 3 + 4] - a1;
        d2 = xb[rown * 3 + 5] - a2;
        pp = fmaf(s0, d0 * d0, fmaf(s1, d1 * d1, s2 * (d2 * d2)));
        const float eo1 = exp2f(-pp);
        l += eo0 + eo1;
        const float ex0 = __shfl_xor(eo0, 16, 64);   // partner's rows
        const float ex1 = __shfl_xor(eo1, 16, 64);

        ACC16(eo0, yb + rown * 32 + dg16);
        ACC16(eo1, yb + (rown + 1) * 32 + dg16);
        ACC16(ex0, yb + rowo * 32 + dg16);
        ACC16(ex1, yb + (rowo + 1) * 32 + dg16);

        if (t < 14)                      // buf just freed; same-wave DS order
            ((float4*)(ycw + (t & 1) * 256))[lane] = ynext;
    }

    // ---- merge dg-pair l, merge ns pairs, 8-slot combine, write ----
    l += __shfl_xor(l, 16, 64);          // l was dg-split by the e-dedup
#pragma unroll
    for (int i = 0; i < 16; ++i) acc[i] += __shfl_xor(acc[i], 32, 64);
    l += __shfl_xor(l, 32, 64);

    if (ns == 0) {
#pragma unroll
        for (int i = 0; i < 16; ++i)
            smem[CMB + (wv * 16 + tl) * 33 + dg16 + i] = acc[i];
        if (dg == 0) smem[SL + wv * 16 + tl] = l;
    }
    __syncthreads();
    {
        const int rtl = tid >> 5, d = tid & 31;   // each thread owns one output
        float ssum = 0.f, lsum = 0.f;
#pragma unroll
        for (int ww = 0; ww < 8; ++ww) {
            ssum += smem[CMB + (ww * 16 + rtl) * 33 + d];
            lsum += smem[SL + ww * 16 + rtl];
        }
        out[(size_t)(t0 + rtl) * DYY + d] = ssum / lsum;
    }
}

extern "C" void kernel_launch(void* const* d_in, const int* in_sizes, int n_in,
                              void* d_out, int out_size, void* d_ws, size_t ws_size,
                              hipStream_t stream) {
    const float* xc = (const float*)d_in[0];
    const float* yc = (const float*)d_in[1];
    const float* xt = (const float*)d_in[2];
    const float* W0 = (const float*)d_in[3];
    const float* b0 = (const float*)d_in[4];
    const float* W1 = (const float*)d_in[5];
    const float* b1 = (const float*)d_in[6];
    const float* W2 = (const float*)d_in[7];
    const float* b2 = (const float*)d_in[8];
    const float* W3 = (const float*)d_in[9];
    const float* b3 = (const float*)d_in[10];
    float* out = (float*)d_out;

    k_fused<<<dim3(BB * NTT / NTB), dim3(512), 0, stream>>>(xc, yc, xt, W0, b0,
                                                            W1, b1, W2, b2, W3,
                                                            b3, out);
}

// Round 4
// 106.736 us; speedup vs baseline: 2.1298x; 2.1298x over previous
//
#include <hip/hip_runtime.h>
#include <math.h>

#define BB 8
#define NCC 1024
#define NTT 1024
#define HH 128
#define DYY 32
#define NTB 16                   // 512 blocks x 512 threads -> 2 blocks/CU
#define LOG2E 1.44269504088896340736f

// LDS arena: 13808 floats = 55.2 KB (x2 blocks = 110 KB <= 160 KB/CU).
//   HB   [0,2112)      h: 16 x 132 (cross-wave shared -> the ONLY barriers)
//   RED  [2112,2496)   8 waves x 48 sig partials
//   WCH  [2496,6592)   8 waves x 2 bufs x 256: wave-PRIVATE W chunks (phase 1)
//   YCB  [6592,10688)  8 waves x 2 bufs x 256: wave-PRIVATE yc tiles (phase 2)
//   XCB  [10688,13760) 8 waves x 384: wave-private xc rows (phase 2)
//   SIGL [13760,13808)
//   CMB  [0,4224) + SL [4224,4352): epilogue, aliases HB/RED/WCH (all dead;
//        disjoint from YCB/XCB/SIGL so fast-wave deposits can't race slow waves)
#define HB 0
#define RED 2112
#define WCH 2496
#define YCB 6592
#define XCB 10688
#define SIGL 13760
#define SMEM_SZ 13808
#define CMB 0
#define SL 4224
#define HSTRIDE 132              // mult of 4 (aligned b128); p vs p+8 = 2-way = free

// Wave-autonomous design: W cols [16w,16w+16) and yc rows [128w,128w+128) are
// read ONLY by wave w (no cross-wave sharing), so staging is wave-private LDS
// double-buffering with compiler-managed vmcnt/lgkmcnt -- NO __syncthreads in
// either pipeline. Only h (cross-wave) and sigl need barriers: 5 total.
// r3 lesson: __launch_bounds__(512,4) acted as min-BLOCKS/CU=4 -> 8 waves/EU
// -> VGPR capped at 64 -> ~1.8KB/thread spill -> 477 MB scratch writes/dispatch
// swamped HBM and thrashed L2 (FETCH 5->170 MB). (512,2) keeps the cap >=128.
// Phase 2 e-dedup: each thread computes 2 exp per tile, partner pair comes via
// shfl_xor(16) (dg axis). P<=0 => exp(P)<=1: no max subtraction.

#define ACC16(E, PTR)                                                          \
    do {                                                                       \
        const float4* yv_ = (const float4*)(PTR);                              \
        const float4 q0_ = yv_[0], q1_ = yv_[1], q2_ = yv_[2], q3_ = yv_[3];   \
        acc[0] = fmaf(E, q0_.x, acc[0]);                                       \
        acc[1] = fmaf(E, q0_.y, acc[1]);                                       \
        acc[2] = fmaf(E, q0_.z, acc[2]);                                       \
        acc[3] = fmaf(E, q0_.w, acc[3]);                                       \
        acc[4] = fmaf(E, q1_.x, acc[4]);                                       \
        acc[5] = fmaf(E, q1_.y, acc[5]);                                       \
        acc[6] = fmaf(E, q1_.z, acc[6]);                                       \
        acc[7] = fmaf(E, q1_.w, acc[7]);                                       \
        acc[8] = fmaf(E, q2_.x, acc[8]);                                       \
        acc[9] = fmaf(E, q2_.y, acc[9]);                                       \
        acc[10] = fmaf(E, q2_.z, acc[10]);                                     \
        acc[11] = fmaf(E, q2_.w, acc[11]);                                     \
        acc[12] = fmaf(E, q3_.x, acc[12]);                                     \
        acc[13] = fmaf(E, q3_.y, acc[13]);                                     \
        acc[14] = fmaf(E, q3_.z, acc[14]);                                     \
        acc[15] = fmaf(E, q3_.w, acc[15]);                                     \
    } while (0)

__global__ __launch_bounds__(512, 2) void k_fused(const float* __restrict__ xc,
                                                  const float* __restrict__ yc,
                                                  const float* __restrict__ xt,
                                                  const float* __restrict__ W0,
                                                  const float* __restrict__ b0,
                                                  const float* __restrict__ W1,
                                                  const float* __restrict__ b1,
                                                  const float* __restrict__ W2,
                                                  const float* __restrict__ b2,
                                                  const float* __restrict__ W3,
                                                  const float* __restrict__ b3,
                                                  float* __restrict__ out) {
    const int tid = threadIdx.x;
    const int t0 = blockIdx.x * NTB;     // global target base (xt/out flat B*Nt)
    const int b = blockIdx.x >> 6;       // 64 blocks per batch
    const int wv = tid >> 6;             // wave 0..7
    const int lane = tid & 63;

    __shared__ float smem[SMEM_SZ];

    const float4* __restrict__ ycG4 = (const float4*)(yc + (size_t)b * NCC * DYY);
    const float4* __restrict__ xcG4 = (const float4*)(xc + (size_t)b * NCC * 3);

    float* ycw = smem + YCB + wv * 512;  // wave-private: 2 bufs x 256 floats
    float* xcw = smem + XCB + wv * 384;  // wave-private: 128 rows x 3
    const int ybase = wv * 1024;         // f4 index of wave's first yc row

    // ---- phase-2 staging loads issued FIRST: latency hides under phase 1 ----
    float4 ty0 = ycG4[ybase + lane];            // tile 0
    float4 ty1 = ycG4[ybase + 64 + lane];       // tile 1
    float4 tx0, tx1;
    if (lane < 48) {
        tx0 = xcG4[wv * 96 + lane];
        tx1 = xcG4[wv * 96 + 48 + lane];
    }

    // ================= phase 1: MLP =================
    const int jg = tid >> 4;             // 0..31 col-group (4 cols)
    const int p = tid & 15;              // 0..15 point
    const int j0 = jg * 4;
    const int jl4 = (jg & 3) * 4;        // col offset within the wave's W slice
    float* hrow = smem + HB + p * HSTRIDE;

    // ---- L0 (W0 columns as float4, broadcast) ----
    {
        const float* xr = xt + (size_t)(t0 + p) * 3;
        const float x0 = xr[0], x1 = xr[1], x2 = xr[2];
        const float4* W0v = (const float4*)W0;
        const float4 w0a = W0v[jg], w0b = W0v[32 + jg], w0c = W0v[64 + jg];
        const float4 bb0 = ((const float4*)b0)[jg];
        float4 h0;
        h0.x = fmaxf(fmaf(x0, w0a.x, fmaf(x1, w0b.x, fmaf(x2, w0c.x, bb0.x))), 0.f);
        h0.y = fmaxf(fmaf(x0, w0a.y, fmaf(x1, w0b.y, fmaf(x2, w0c.y, bb0.y))), 0.f);
        h0.z = fmaxf(fmaf(x0, w0a.z, fmaf(x1, w0b.z, fmaf(x2, w0c.z, bb0.z))), 0.f);
        h0.w = fmaxf(fmaf(x0, w0a.w, fmaf(x1, w0b.w, fmaf(x2, w0c.w, bb0.w))), 0.f);
        *(float4*)(hrow + j0) = h0;
    }

    // ---- park phase-2 staged data in its (disjoint) LDS while L0 settles ----
    ((float4*)ycw)[lane] = ty0;
    ((float4*)(ycw + 256))[lane] = ty1;
    if (lane < 48) {
        ((float4*)xcw)[lane] = tx0;
        ((float4*)xcw)[lane + 48] = tx1;
    }

    // wave-private W chunk pipeline: chunk = 16 k-rows x 16 cols = 1 f4/lane
    const int gWb = (lane >> 2) * 32 + wv * 4 + (lane & 3);
    float* wwb = smem + WCH + wv * 512;
    const float4* __restrict__ W1v = (const float4*)W1;
    const float4* __restrict__ W2v = (const float4*)W2;

    // L1 prologue loads BEFORE the barrier (independent of LDS)
    float4 wA0 = W1v[gWb], wA1 = W1v[gWb + 512];
    __syncthreads();                     // h(L0) visible to all waves

    auto run_layer = [&](const float4* __restrict__ Wv, const float4 bi,
                         float4 r0, float4 r1) -> float4 {
        float a0 = bi.x, a1 = bi.y, a2 = bi.z, a3 = bi.w;
        ((float4*)wwb)[lane] = r0;       // buf0 = chunk 0 (waits its vmcnt)
        float4 wcur = r1;                // chunk 1 pending in reg
#pragma unroll
        for (int c = 0; c < 8; ++c) {
            float4 wnext;
            if (c < 6) wnext = Wv[gWb + (c + 2) * 512];           // issue early
            if (c < 7) ((float4*)(wwb + ((c + 1) & 1) * 256))[lane] = wcur;
            const float* wbc = wwb + (c & 1) * 256;
#pragma unroll
            for (int q = 0; q < 4; ++q) {
                const float4 ch = *(const float4*)(hrow + c * 16 + q * 4);
                const float4 k0 = *(const float4*)(wbc + (q * 4 + 0) * 16 + jl4);
                const float4 k1 = *(const float4*)(wbc + (q * 4 + 1) * 16 + jl4);
                const float4 k2 = *(const float4*)(wbc + (q * 4 + 2) * 16 + jl4);
                const float4 k3 = *(const float4*)(wbc + (q * 4 + 3) * 16 + jl4);
                a0 = fmaf(ch.x, k0.x, a0);
                a1 = fmaf(ch.x, k0.y, a1);
                a2 = fmaf(ch.x, k0.z, a2);
                a3 = fmaf(ch.x, k0.w, a3);
                a0 = fmaf(ch.y, k1.x, a0);
                a1 = fmaf(ch.y, k1.y, a1);
                a2 = fmaf(ch.y, k1.z, a2);
                a3 = fmaf(ch.y, k1.w, a3);
                a0 = fmaf(ch.z, k2.x, a0);
                a1 = fmaf(ch.z, k2.y, a1);
                a2 = fmaf(ch.z, k2.z, a2);
                a3 = fmaf(ch.z, k2.w, a3);
                a0 = fmaf(ch.w, k3.x, a0);
                a1 = fmaf(ch.w, k3.y, a1);
                a2 = fmaf(ch.w, k3.z, a2);
                a3 = fmaf(ch.w, k3.w, a3);
            }
            wcur = wnext;
        }
        float4 r;
        r.x = fmaxf(a0, 0.f);
        r.y = fmaxf(a1, 0.f);
        r.z = fmaxf(a2, 0.f);
        r.w = fmaxf(a3, 0.f);
        return r;
    };

    float4 oL1 = run_layer(W1v, ((const float4*)b1)[jg], wA0, wA1);
    float4 wB0 = W2v[gWb], wB1 = W2v[gWb + 512];   // L2 prologue before barriers
    __syncthreads();                     // all h(L0) reads done
    *(float4*)(hrow + j0) = oL1;
    __syncthreads();                     // h(L1) visible
    float4 oL2 = run_layer(W2v, ((const float4*)b2)[jg], wB0, wB1);

    // ---- L3 + shfl-reduce over jg + exp -> sig*log2e ----
    {
        const float4* W3v = (const float4*)W3;
        const float4 wr0 = W3v[jg * 3 + 0];
        const float4 wr1 = W3v[jg * 3 + 1];
        const float4 wr2 = W3v[jg * 3 + 2];
        float p0 = oL2.x * wr0.x + oL2.y * wr0.w + oL2.z * wr1.z + oL2.w * wr2.y;
        float p1 = oL2.x * wr0.y + oL2.y * wr1.x + oL2.z * wr1.w + oL2.w * wr2.z;
        float p2 = oL2.x * wr0.z + oL2.y * wr1.y + oL2.z * wr2.x + oL2.w * wr2.w;
        p0 += __shfl_xor(p0, 16, 64);    // lane bits 4,5 = jg&3: reduce 4 jg
        p0 += __shfl_xor(p0, 32, 64);
        p1 += __shfl_xor(p1, 16, 64);
        p1 += __shfl_xor(p1, 32, 64);
        p2 += __shfl_xor(p2, 16, 64);
        p2 += __shfl_xor(p2, 32, 64);
        if (lane < 16) {                 // lane = p here
            smem[RED + wv * 48 + lane * 3 + 0] = p0;
            smem[RED + wv * 48 + lane * 3 + 1] = p1;
            smem[RED + wv * 48 + lane * 3 + 2] = p2;
        }
    }
    __syncthreads();
    if (tid < 48) {
        const int r = tid / 3, cix = tid - r * 3;
        float v = b3[cix];
#pragma unroll
        for (int g = 0; g < 8; ++g) v += smem[RED + g * 48 + r * 3 + cix];
        smem[SIGL + r * 3 + cix] = __expf(v) * LOG2E;
    }
    __syncthreads();                     // sigl ready; phase-1 arenas dead

    // ========== phase 2: attention, wave-autonomous, ZERO barriers ==========
    const int tl = lane & 15;            // target within block
    const int dg = (lane >> 4) & 1;      // d-half
    const int ns = lane >> 5;            // n-half within the wave's 8-row tile
    const int dg16 = dg * 16;
    const int rown = ns * 4 + dg * 2;        // own e rows
    const int rowo = ns * 4 + 2 - dg * 2;    // partner e rows (via shfl)

    const float s0 = smem[SIGL + tl * 3 + 0];
    const float s1 = smem[SIGL + tl * 3 + 1];
    const float s2 = smem[SIGL + tl * 3 + 2];
    const float* ar = xt + (size_t)(t0 + tl) * 3;
    const float a0 = ar[0], a1 = ar[1], a2 = ar[2];

    float acc[16];
#pragma unroll
    for (int i = 0; i < 16; ++i) acc[i] = 0.f;
    float l = 0.f;

#pragma unroll 2
    for (int t = 0; t < 16; ++t) {
        float4 ynext;
        if (t < 14) ynext = ycG4[ybase + (t + 2) * 64 + lane];   // issue early
        const float* yb = ycw + (t & 1) * 256;
        const float* xb = xcw + t * 24;

        float d0 = xb[rown * 3 + 0] - a0;
        float d1 = xb[rown * 3 + 1] - a1;
        float d2 = xb[rown * 3 + 2] - a2;
        float pp = fmaf(s0, d0 * d0, fmaf(s1, d1 * d1, s2 * (d2 * d2)));
        const float eo0 = exp2f(-pp);
        d0 = xb[rown * 3 + 3] - a0;
        d1 = xb[rown * 3 + 4] - a1;
        d2 = xb[rown * 3 + 5] - a2;
        pp = fmaf(s0, d0 * d0, fmaf(s1, d1 * d1, s2 * (d2 * d2)));
        const float eo1 = exp2f(-pp);
        l += eo0 + eo1;
        const float ex0 = __shfl_xor(eo0, 16, 64);   // partner's rows
        const float ex1 = __shfl_xor(eo1, 16, 64);

        ACC16(eo0, yb + rown * 32 + dg16);
        ACC16(eo1, yb + (rown + 1) * 32 + dg16);
        ACC16(ex0, yb + rowo * 32 + dg16);
        ACC16(ex1, yb + (rowo + 1) * 32 + dg16);

        if (t < 14)                      // buf just freed; same-wave DS order
            ((float4*)(ycw + (t & 1) * 256))[lane] = ynext;
    }

    // ---- merge dg-pair l, merge ns pairs, 8-slot combine, write ----
    l += __shfl_xor(l, 16, 64);          // l was dg-split by the e-dedup
#pragma unroll
    for (int i = 0; i < 16; ++i) acc[i] += __shfl_xor(acc[i], 32, 64);
    l += __shfl_xor(l, 32, 64);

    if (ns == 0) {
#pragma unroll
        for (int i = 0; i < 16; ++i)
            smem[CMB + (wv * 16 + tl) * 33 + dg16 + i] = acc[i];
        if (dg == 0) smem[SL + wv * 16 + tl] = l;
    }
    __syncthreads();
    {
        const int rtl = tid >> 5, d = tid & 31;   // each thread owns one output
        float ssum = 0.f, lsum = 0.f;
#pragma unroll
        for (int ww = 0; ww < 8; ++ww) {
            ssum += smem[CMB + (ww * 16 + rtl) * 33 + d];
            lsum += smem[SL + ww * 16 + rtl];
        }
        out[(size_t)(t0 + rtl) * DYY + d] = ssum / lsum;
    }
}

extern "C" void kernel_launch(void* const* d_in, const int* in_sizes, int n_in,
                              void* d_out, int out_size, void* d_ws, size_t ws_size,
                              hipStream_t stream) {
    const float* xc = (const float*)d_in[0];
    const float* yc = (const float*)d_in[1];
    const float* xt = (const float*)d_in[2];
    const float* W0 = (const float*)d_in[3];
    const float* b0 = (const float*)d_in[4];
    const float* W1 = (const float*)d_in[5];
    const float* b1 = (const float*)d_in[6];
    const float* W2 = (const float*)d_in[7];
    const float* b2 = (const float*)d_in[8];
    const float* W3 = (const float*)d_in[9];
    const float* b3 = (const float*)d_in[10];
    float* out = (float*)d_out;

    k_fused<<<dim3(BB * NTT / NTB), dim3(512), 0, stream>>>(xc, yc, xt, W0, b0,
                                                            W1, b1, W2, b2, W3,
                                                            b3, out);
}